// Round 6
// baseline (529.125 us; speedup 1.0000x reference)
//
#include <hip/hip_runtime.h>
#include <hip/hip_bf16.h>
#include <hip/hip_fp16.h>

// ---------------------------------------------------------------------------
// DyadXLSTM forward. fp32 in/out; bf16 activations into MFMA GEMMs.
// mLSTM recurrence computed as chunked causal attention (exact rewrite):
//   F_t = cumsum(fp), a_t = ip_t - F_t, M_t = max(0, prefix-max a),
//   P_tj = exp(a_j - M_t) * (q_t . k_j)  [j<=t],  h = sig(o) * P V / max(|rowsum P|,1)
// sLSTM: MFMA-batched. One block per head (4 blocks x 8 waves). Per step the
// recurrence matvec for ALL 32 batches is one 32x64 @ 64x64 GEMM per gate
// (8 MFMA 16x16x32 per wave, R^T fragments resident in VGPRs). Each wave owns
// one (M-tile,N-tile) and ALL 4 gates -> gate nonlinearity entirely in-lane,
// no cross-wave gate exchange. h double-buffered in LDS, 1 barrier/step.
// B=32 T=256 NH=4 DH=64 D=H=256, BT=8192.
// ---------------------------------------------------------------------------

#define BT 8192
#define SZ ((size_t)BT * 256)

typedef __attribute__((ext_vector_type(4))) float  f32x4;
typedef __attribute__((ext_vector_type(8))) short  s16x8;

__device__ __forceinline__ float bf2f(unsigned short u) {
    return __uint_as_float(((unsigned int)u) << 16);
}
__device__ __forceinline__ unsigned short f2bf(float f) {
    __hip_bfloat16 h = __float2bfloat16(f);
    return *(unsigned short*)&h;
}

// ---------------------------------------------------------------------------
// Convert+transpose 15 weight matrices (256x256 fp32 K-major) -> bf16 Wt[slot][N][K]
__global__ __launch_bounds__(256) void conv_w(
    const float* mWq, const float* mWk, const float* mWv, const float* mWo,
    const float* mWp, const float* sWz, const float* sWi, const float* sWf,
    const float* sWo, const float* sWp, unsigned short* __restrict__ Wt)
{
    int z = blockIdx.z;
    const float* mp[5] = {mWq, mWk, mWv, mWo, mWp};
    const float* sp[5] = {sWz, sWi, sWf, sWo, sWp};
    const float* src;
    if (z < 5)       src = mp[z];
    else if (z < 10) src = sp[z - 5];
    else             src = mp[z - 10] + 65536;
    int kB = blockIdx.x * 64, nB = blockIdx.y * 64;
    __shared__ unsigned short Ts[64][68];
    int tid = threadIdx.x;
    int r = tid >> 2, c = (tid & 3) * 16;
    #pragma unroll
    for (int j = 0; j < 16; j += 4) {
        float4 wv = *(const float4*)(src + (size_t)(kB + r) * 256 + nB + c + j);
        Ts[r][c + j]     = f2bf(wv.x); Ts[r][c + j + 1] = f2bf(wv.y);
        Ts[r][c + j + 2] = f2bf(wv.z); Ts[r][c + j + 3] = f2bf(wv.w);
    }
    __syncthreads();
    int n = tid >> 2, k0 = (tid & 3) * 16;
    __attribute__((aligned(16))) unsigned short tmp[16];
    #pragma unroll
    for (int j = 0; j < 16; ++j) tmp[j] = Ts[k0 + j][n];
    unsigned short* dst = Wt + (size_t)z * 65536 + (size_t)(nB + n) * 256 + kB + k0;
    *(uint4*)dst       = *(const uint4*)tmp;
    *(uint4*)(dst + 8) = *(const uint4*)(tmp + 8);
}

// ---------------------------------------------------------------------------
__global__ __launch_bounds__(256) void build_x(
    const float* __restrict__ X, const int* __restrict__ dyad,
    const float* __restrict__ embed, float* __restrict__ x)
{
    int i = blockIdx.x * 256 + threadIdx.x;
    int d = i & 255, bt = i >> 8, b = bt >> 8;
    x[i] = (d < 224) ? X[bt * 224 + d] : embed[dyad[b] * 32 + (d - 224)];
}

// ---------------------------------------------------------------------------
__global__ __launch_bounds__(256) void layernorm(
    const float* __restrict__ x, const float* __restrict__ g,
    const float* __restrict__ b, unsigned short* __restrict__ xn)
{
    int row = blockIdx.x, tid = threadIdx.x;
    float v = x[(size_t)row * 256 + tid];
    float s = v, s2 = v * v;
    #pragma unroll
    for (int o = 32; o; o >>= 1) { s += __shfl_xor(s, o); s2 += __shfl_xor(s2, o); }
    __shared__ float ls[8];
    int wave = tid >> 6, lane = tid & 63;
    if (lane == 0) { ls[wave] = s; ls[4 + wave] = s2; }
    __syncthreads();
    s  = ls[0] + ls[1] + ls[2] + ls[3];
    s2 = ls[4] + ls[5] + ls[6] + ls[7];
    float mu  = s * (1.f / 256.f);
    float var = s2 * (1.f / 256.f) - mu * mu;
    float inv = rsqrtf(var + 1e-5f);
    xn[(size_t)row * 256 + tid] = f2bf((v - mu) * inv * g[tid] + b[tid]);
}

// ---------------------------------------------------------------------------
// bf16-out GEMM: out[z][8192][256](bf16) = alpha_z * A(bf16) @ Wt[slot0+z]^T
__global__ __launch_bounds__(256) void gemm_mfma_bf16(
    const unsigned short* __restrict__ A, const unsigned short* __restrict__ Wt,
    int slot0, unsigned short* out0, float a0, float a1, float a2, float a3)
{
    __shared__ unsigned short As[64 * 40];
    __shared__ unsigned short Bs[64 * 40];
    int tid = threadIdx.x, bz = blockIdx.z;
    const unsigned short* W = Wt + (size_t)(slot0 + bz) * 65536;
    unsigned short* out = out0 + (size_t)bz * SZ;
    float alpha = bz == 0 ? a0 : bz == 1 ? a1 : bz == 2 ? a2 : a3;
    int rowBase = blockIdx.x * 64, colBase = blockIdx.y * 64;
    int srow = tid >> 2, scol = (tid & 3) * 8;
    const unsigned short* Ap = A + (size_t)(rowBase + srow) * 256 + scol;
    const unsigned short* Wp = W + (size_t)(colBase + srow) * 256 + scol;
    unsigned short* Asw = As + srow * 40 + scol;
    unsigned short* Bsw = Bs + srow * 40 + scol;
    int w = tid >> 6, lane = tid & 63, quad = lane >> 4, l15 = lane & 15;
    const unsigned short* Ar  = As + (w * 16 + l15) * 40 + quad * 8;
    const unsigned short* Br0 = Bs + l15 * 40 + quad * 8;
    f32x4 acc[4];
    #pragma unroll
    for (int c = 0; c < 4; ++c) acc[c] = (f32x4){0.f, 0.f, 0.f, 0.f};
    for (int k0 = 0; k0 < 256; k0 += 32) {
        uint4 av = *(const uint4*)(Ap + k0);
        uint4 bv = *(const uint4*)(Wp + k0);
        __syncthreads();
        *(uint4*)Asw = av;
        *(uint4*)Bsw = bv;
        __syncthreads();
        s16x8 af = *(const s16x8*)Ar;
        #pragma unroll
        for (int c = 0; c < 4; ++c) {
            s16x8 bf = *(const s16x8*)(Br0 + c * 16 * 40);
            acc[c] = __builtin_amdgcn_mfma_f32_16x16x32_bf16(af, bf, acc[c], 0, 0, 0);
        }
    }
    #pragma unroll
    for (int c = 0; c < 4; ++c) {
        int col  = colBase + c * 16 + l15;
        int row0 = rowBase + w * 16 + quad * 4;
        #pragma unroll
        for (int i2 = 0; i2 < 4; ++i2)
            out[(size_t)(row0 + i2) * 256 + col] = f2bf(alpha * acc[c][i2]);
    }
}

// ---------------------------------------------------------------------------
// fp32-out GEMM with residual: out = A(bf16) @ Wt[slot]^T + Res
__global__ __launch_bounds__(256) void gemm_mfma_f32(
    const unsigned short* __restrict__ A, const unsigned short* __restrict__ Wt,
    int slot, float* __restrict__ out, const float* __restrict__ Res)
{
    __shared__ unsigned short As[64 * 40];
    __shared__ unsigned short Bs[64 * 40];
    int tid = threadIdx.x;
    const unsigned short* W = Wt + (size_t)slot * 65536;
    int rowBase = blockIdx.x * 64, colBase = blockIdx.y * 64;
    int srow = tid >> 2, scol = (tid & 3) * 8;
    const unsigned short* Ap = A + (size_t)(rowBase + srow) * 256 + scol;
    const unsigned short* Wp = W + (size_t)(colBase + srow) * 256 + scol;
    unsigned short* Asw = As + srow * 40 + scol;
    unsigned short* Bsw = Bs + srow * 40 + scol;
    int w = tid >> 6, lane = tid & 63, quad = lane >> 4, l15 = lane & 15;
    const unsigned short* Ar  = As + (w * 16 + l15) * 40 + quad * 8;
    const unsigned short* Br0 = Bs + l15 * 40 + quad * 8;
    f32x4 acc[4];
    #pragma unroll
    for (int c = 0; c < 4; ++c) acc[c] = (f32x4){0.f, 0.f, 0.f, 0.f};
    for (int k0 = 0; k0 < 256; k0 += 32) {
        uint4 av = *(const uint4*)(Ap + k0);
        uint4 bv = *(const uint4*)(Wp + k0);
        __syncthreads();
        *(uint4*)Asw = av;
        *(uint4*)Bsw = bv;
        __syncthreads();
        s16x8 af = *(const s16x8*)Ar;
        #pragma unroll
        for (int c = 0; c < 4; ++c) {
            s16x8 bf = *(const s16x8*)(Br0 + c * 16 * 40);
            acc[c] = __builtin_amdgcn_mfma_f32_16x16x32_bf16(af, bf, acc[c], 0, 0, 0);
        }
    }
    #pragma unroll
    for (int c = 0; c < 4; ++c) {
        int col  = colBase + c * 16 + l15;
        int row0 = rowBase + w * 16 + quad * 4;
        #pragma unroll
        for (int i2 = 0; i2 < 4; ++i2) {
            size_t idx = (size_t)(row0 + i2) * 256 + col;
            out[idx] = acc[c][i2] + Res[idx];
        }
    }
}

// ---------------------------------------------------------------------------
// gi/gf[row,h] = xn[row,:].W{i,f}[:,h] + b{i,f}[h]
__global__ __launch_bounds__(256) void gate_gemm(
    const unsigned short* __restrict__ xn,
    const float* __restrict__ Wi, const float* __restrict__ Wf,
    const float* __restrict__ bi, const float* __restrict__ bf_,
    float* __restrict__ gi, float* __restrict__ gf)
{
    int tid = threadIdx.x;
    int hh = tid & 3;
    int row = blockIdx.x * 64 + (tid >> 2);
    float ai = bi[hh], af = bf_[hh];
    const unsigned short* xr = xn + (size_t)row * 256;
    for (int k2 = 0; k2 < 256; ++k2) {
        float xv = bf2f(xr[k2]);
        ai += xv * Wi[k2 * 4 + hh];
        af += xv * Wf[k2 * 4 + hh];
    }
    gi[row * 4 + hh] = ai;
    gf[row * 4 + hh] = af;
}

// ---------------------------------------------------------------------------
// Per-(b,h): F = cumsum(fp); a = ip - F; M = max(0, prefix-max(a)).
// One block per bh, thread = t, Hillis-Steele scans in LDS.
__global__ __launch_bounds__(256) void scan_am(
    const float* __restrict__ gi, const float* __restrict__ gf,
    float* __restrict__ a_arr, float* __restrict__ M_arr)
{
    int bh = blockIdx.x, b = bh >> 2, h = bh & 3;
    int t = threadIdx.x;
    float fp = gf[(b * 256 + t) * 4 + h];
    float ip = gi[(b * 256 + t) * 4 + h];
    __shared__ float buf[256];
    buf[t] = fp;
    __syncthreads();
    #pragma unroll
    for (int o = 1; o < 256; o <<= 1) {
        float add = (t >= o) ? buf[t - o] : 0.f;
        __syncthreads();
        buf[t] += add;
        __syncthreads();
    }
    float F = buf[t];
    float a = ip - F;
    __syncthreads();
    buf[t] = a;
    __syncthreads();
    #pragma unroll
    for (int o = 1; o < 256; o <<= 1) {
        float mx = (t >= o) ? buf[t - o] : -3.4e38f;
        __syncthreads();
        buf[t] = fmaxf(buf[t], mx);
        __syncthreads();
    }
    a_arr[bh * 256 + t] = a;
    M_arr[bh * 256 + t] = fmaxf(buf[t], 0.f);
}

// ---------------------------------------------------------------------------
// mLSTM as causal decay-attention. Block = (bh, row-tile rt of 64).
// 4 waves; wave w owns rows [16w,16w+16) of the row tile.
__global__ __launch_bounds__(256) void mlstm_attn(
    const unsigned short* __restrict__ qb, const unsigned short* __restrict__ kb,
    const unsigned short* __restrict__ vb, const unsigned short* __restrict__ ob,
    const float* __restrict__ a_arr, const float* __restrict__ M_arr,
    unsigned short* __restrict__ hout)
{
    int bh = blockIdx.x, rt = blockIdx.y;
    int b = bh >> 2, h = bh & 3;
    int tid = threadIdx.x, w = tid >> 6, lane = tid & 63;
    int quad = lane >> 4, l15 = lane & 15;
    __shared__ unsigned short Qs[64][72];
    __shared__ unsigned short Ks[64][72];
    __shared__ unsigned short Vt[64][72];      // V transposed: [d][j]
    __shared__ unsigned short Ps[4][16][72];   // per-wave P strip
    __shared__ float a_s[64], M_s[64];
    int sr = tid >> 2, sc = (tid & 3) * 16;
    size_t qoff = (size_t)(b * 256 + rt * 64 + sr) * 256 + h * 64 + sc;
    *(uint4*)&Qs[sr][sc]     = *(const uint4*)(qb + qoff);
    *(uint4*)&Qs[sr][sc + 8] = *(const uint4*)(qb + qoff + 8);
    if (tid < 64) M_s[tid] = M_arr[bh * 256 + rt * 64 + tid];
    f32x4 accN[4];
    #pragma unroll
    for (int c = 0; c < 4; ++c) accN[c] = (f32x4){0.f, 0.f, 0.f, 0.f};
    f32x4 den = (f32x4){0.f, 0.f, 0.f, 0.f};
    int rowT = w * 16 + quad * 4;              // row within 64-tile (+i2)
    for (int ct = 0; ct <= rt; ++ct) {
        // stage K, V^T, a for this j-tile
        size_t koff = (size_t)(b * 256 + ct * 64 + sr) * 256 + h * 64 + sc;
        uint4 kv0 = *(const uint4*)(kb + koff);
        uint4 kv1 = *(const uint4*)(kb + koff + 8);
        uint4 vv0 = *(const uint4*)(vb + koff);
        uint4 vv1 = *(const uint4*)(vb + koff + 8);
        *(uint4*)&Ks[sr][sc]     = kv0;
        *(uint4*)&Ks[sr][sc + 8] = kv1;
        __attribute__((aligned(16))) unsigned short vt[16];
        *(uint4*)vt = vv0; *(uint4*)(vt + 8) = vv1;
        #pragma unroll
        for (int jj = 0; jj < 16; ++jj) Vt[sc + jj][sr] = vt[jj];
        if (tid < 64) a_s[tid] = a_arr[bh * 256 + ct * 64 + tid];
        __syncthreads();
        // S = Q K^T (16x64 strip per wave)
        f32x4 S[4];
        #pragma unroll
        for (int c = 0; c < 4; ++c) S[c] = (f32x4){0.f, 0.f, 0.f, 0.f};
        #pragma unroll
        for (int ks = 0; ks < 2; ++ks) {
            s16x8 af = *(const s16x8*)&Qs[w * 16 + l15][quad * 8 + ks * 32];
            #pragma unroll
            for (int c = 0; c < 4; ++c) {
                s16x8 bfr = *(const s16x8*)&Ks[c * 16 + l15][quad * 8 + ks * 32];
                S[c] = __builtin_amdgcn_mfma_f32_16x16x32_bf16(af, bfr, S[c], 0, 0, 0);
            }
        }
        // scale by exp(a_j - M_t), causal mask on diagonal tile, rowsum
        bool dg = (ct == rt);
        #pragma unroll
        for (int c = 0; c < 4; ++c) {
            int col = c * 16 + l15;
            #pragma unroll
            for (int i2 = 0; i2 < 4; ++i2) {
                int row = rowT + i2;
                float p = S[c][i2] * __expf(a_s[col] - M_s[row]);
                if (dg && col > row) p = 0.f;
                S[c][i2] = p;
                den[i2] += p;
            }
        }
        // P -> LDS (bf16) for A-fragment relayout
        #pragma unroll
        for (int c = 0; c < 4; ++c)
            #pragma unroll
            for (int i2 = 0; i2 < 4; ++i2)
                Ps[w][quad * 4 + i2][c * 16 + l15] = f2bf(S[c][i2]);
        __syncthreads();
        // num += P V
        #pragma unroll
        for (int ks = 0; ks < 2; ++ks) {
            s16x8 af = *(const s16x8*)&Ps[w][l15][quad * 8 + ks * 32];
            #pragma unroll
            for (int c = 0; c < 4; ++c) {
                s16x8 bfr = *(const s16x8*)&Vt[c * 16 + l15][quad * 8 + ks * 32];
                accN[c] = __builtin_amdgcn_mfma_f32_16x16x32_bf16(af, bfr, accN[c], 0, 0, 0);
            }
        }
        __syncthreads();
    }
    // reduce den across the 16 lanes sharing rows (l15 dimension)
    #pragma unroll
    for (int ofs = 1; ofs < 16; ofs <<= 1) {
        den[0] += __shfl_xor(den[0], ofs);
        den[1] += __shfl_xor(den[1], ofs);
        den[2] += __shfl_xor(den[2], ofs);
        den[3] += __shfl_xor(den[3], ofs);
    }
    // epilogue: h = sigmoid(o) * num / max(|den|,1)
    #pragma unroll
    for (int c = 0; c < 4; ++c) {
        int d = c * 16 + l15;
        #pragma unroll
        for (int i2 = 0; i2 < 4; ++i2) {
            size_t idx = (size_t)(b * 256 + rt * 64 + rowT + i2) * 256 + h * 64 + d;
            float ov = bf2f(ob[idx]);
            float sg = 1.f / (1.f + __expf(-ov));
            float dn = fmaxf(fabsf(den[i2]), 1.f);
            hout[idx] = f2bf(sg * accN[c][i2] / dn);
        }
    }
}

// ---------------------------------------------------------------------------
// sLSTM scan, MFMA-batched. ONE block per head (grid=4), 8 waves (512 thr).
// Wave w -> M-tile mt=w>>2 (16 batches), N-tile nt=w&3 (16 e's), ALL 4 gates:
// per step 8 MFMA 16x16x32 (4 gates x 2 K-steps) with R^T fragments resident
// in VGPRs. C-fragment layout puts z,i,f,o for a lane's 4 (b,e) pairs in the
// lane's own registers -> pointwise gate math fully in-lane, no exchange.
// h (bf16) double-buffered in LDS [2][32][72]; ONE barrier per step.
// Gate x-preacts prefetched 1 step ahead and used as MFMA C-init.
__global__ __launch_bounds__(512) void slstm_scan(
    const unsigned short* __restrict__ zx, const unsigned short* __restrict__ ix,
    const unsigned short* __restrict__ fx, const unsigned short* __restrict__ ox,
    const float* __restrict__ Rz, const float* __restrict__ Ri,
    const float* __restrict__ Rf, const float* __restrict__ Ro,
    unsigned short* __restrict__ hout)
{
    int hd = blockIdx.x;
    int tid = threadIdx.x, w = tid >> 6, lane = tid & 63;
    int mt = w >> 2, nt = w & 3, quad = lane >> 4, l15 = lane & 15;
    __shared__ unsigned short hbuf[2][32][72];   // 9216 B, double-buffered h

    // --- B-operand: R_g^T fragments, resident in VGPRs (one-time load) ---
    // B[n=e][k=d] = R_g[d][e]; frag elem j = R_g[ks*32+quad*8+j][nt*16+l15]
    const float* Rg0 = Rz + hd * 4096;
    const float* Rg1 = Ri + hd * 4096;
    const float* Rg2 = Rf + hd * 4096;
    const float* Rg3 = Ro + hd * 4096;
    int ecol = nt * 16 + l15;
    s16x8 bfrag[4][2];
    #pragma unroll
    for (int ks = 0; ks < 2; ++ks) {
        int dbase = ks * 32 + quad * 8;
        #pragma unroll
        for (int j = 0; j < 8; ++j) {
            int off = (dbase + j) * 64 + ecol;
            bfrag[0][ks][j] = (short)f2bf(Rg0[off]);
            bfrag[1][ks][j] = (short)f2bf(Rg1[off]);
            bfrag[2][ks][j] = (short)f2bf(Rg2[off]);
            bfrag[3][ks][j] = (short)f2bf(Rg3[off]);
        }
    }
    // zero h buffers (t=0 state)
    for (int i = tid; i < 2 * 32 * 72; i += 512)
        ((unsigned short*)hbuf)[i] = 0;

    // --- per-lane (b,e) ownership: b = mt*16 + quad*4 + r, e = ecol ---
    int b0 = mt * 16 + quad * 4;
    const unsigned short* xg0 = zx; const unsigned short* xg1 = ix;
    const unsigned short* xg2 = fx; const unsigned short* xg3 = ox;
    size_t xbase[4];
    #pragma unroll
    for (int r = 0; r < 4; ++r)
        xbase[r] = (size_t)(b0 + r) * 65536 + hd * 64 + ecol;

    // prefetch x-preacts for t=0
    unsigned short xc[4][4];  // [gate][r]
    #pragma unroll
    for (int r = 0; r < 4; ++r) {
        xc[0][r] = xg0[xbase[r]]; xc[1][r] = xg1[xbase[r]];
        xc[2][r] = xg2[xbase[r]]; xc[3][r] = xg3[xbase[r]];
    }
    float cst[4] = {0.f, 0.f, 0.f, 0.f};
    float nst[4] = {0.f, 0.f, 0.f, 0.f};
    float mst[4] = {0.f, 0.f, 0.f, 0.f};
    __syncthreads();

    int cur = 0;
    int arow = mt * 16 + l15;         // A-fragment row in hbuf
    for (int t = 0; t < 256; ++t) {
        // prefetch x-preacts for t+1 (consumed next iteration)
        unsigned short xnx[4][4];
        size_t toff = (size_t)((t + 1 < 256) ? t + 1 : t) * 256;
        #pragma unroll
        for (int r = 0; r < 4; ++r) {
            xnx[0][r] = xg0[xbase[r] + toff]; xnx[1][r] = xg1[xbase[r] + toff];
            xnx[2][r] = xg2[xbase[r] + toff]; xnx[3][r] = xg3[xbase[r] + toff];
        }
        // A fragments: h[cur][b=arow][d = ks*32 + quad*8 .. +7]
        s16x8 af0 = *(const s16x8*)&hbuf[cur][arow][quad * 8];
        s16x8 af1 = *(const s16x8*)&hbuf[cur][arow][32 + quad * 8];
        // C init = x-preacts; accumulate h @ R_g
        f32x4 acc[4];
        #pragma unroll
        for (int g = 0; g < 4; ++g)
            acc[g] = (f32x4){bf2f(xc[g][0]), bf2f(xc[g][1]),
                             bf2f(xc[g][2]), bf2f(xc[g][3])};
        #pragma unroll
        for (int g = 0; g < 4; ++g) {
            acc[g] = __builtin_amdgcn_mfma_f32_16x16x32_bf16(af0, bfrag[g][0], acc[g], 0, 0, 0);
            acc[g] = __builtin_amdgcn_mfma_f32_16x16x32_bf16(af1, bfrag[g][1], acc[g], 0, 0, 0);
        }
        // pointwise gate math for the lane's 4 (b,e) pairs
        size_t tstore = (size_t)t * 256;
        #pragma unroll
        for (int r = 0; r < 4; ++r) {
            float zp = acc[0][r], ip2 = acc[1][r];
            float fp = acc[2][r], op  = acc[3][r];
            float ez = __expf(2.f * zp);
            float z  = 1.f - 2.f / (ez + 1.f);          // tanh
            float fpm = fp + mst[r];
            float mn = fmaxf(fpm, ip2);
            float i_s = __expf(ip2 - mn), f_s = __expf(fpm - mn);
            mst[r] = mn;
            cst[r] = f_s * cst[r] + i_s * z;
            nst[r] = f_s * nst[r] + i_s;
            float hv = cst[r] / (nst[r] * (1.f + __expf(-op)));
            unsigned short hb16 = f2bf(hv);
            hbuf[cur ^ 1][b0 + r][ecol] = hb16;          // next-step A source
            hout[xbase[r] + tstore] = hb16;              // global output
        }
        #pragma unroll
        for (int r = 0; r < 4; ++r) {
            xc[0][r] = xnx[0][r]; xc[1][r] = xnx[1][r];
            xc[2][r] = xnx[2][r]; xc[3][r] = xnx[3][r];
        }
        __syncthreads();
        cur ^= 1;
    }
}

// ---------------------------------------------------------------------------
__global__ __launch_bounds__(64) void fc_kernel(
    const float* __restrict__ x, const float* __restrict__ fcW,
    const float* __restrict__ fcb, float* __restrict__ out)
{
    int b = blockIdx.x, lane = threadIdx.x;
    const float* xr = x + ((size_t)b * 256 + 255) * 256;
    float s = 0.f;
    #pragma unroll
    for (int j = 0; j < 4; ++j) { int d = j * 64 + lane; s += xr[d] * fcW[d]; }
    #pragma unroll
    for (int ofs = 32; ofs; ofs >>= 1) s += __shfl_xor(s, ofs);
    if (lane == 0) out[b] = s + fcb[0];
}

// ---------------------------------------------------------------------------
extern "C" void kernel_launch(void* const* d_in, const int* in_sizes, int n_in,
                              void* d_out, int out_size, void* d_ws, size_t ws_size,
                              hipStream_t stream)
{
    const float* X      = (const float*)d_in[0];
    const int*   dyad   = (const int*)d_in[1];
    const float* embed  = (const float*)d_in[2];
    const float* m_ln_g = (const float*)d_in[3];
    const float* m_ln_b = (const float*)d_in[4];
    const float* m_Wq   = (const float*)d_in[5];
    const float* m_Wk   = (const float*)d_in[6];
    const float* m_Wv   = (const float*)d_in[7];
    const float* m_Wi   = (const float*)d_in[8];
    const float* m_Wf   = (const float*)d_in[9];
    const float* m_bi   = (const float*)d_in[10];
    const float* m_bf   = (const float*)d_in[11];
    const float* m_Wo   = (const float*)d_in[12];
    const float* m_Wp   = (const float*)d_in[13];
    const float* s_ln_g = (const float*)d_in[14];
    const float* s_ln_b = (const float*)d_in[15];
    const float* s_Wz   = (const float*)d_in[16];
    const float* s_Wi   = (const float*)d_in[17];
    const float* s_Wf   = (const float*)d_in[18];
    const float* s_Wo   = (const float*)d_in[19];
    const float* s_Rz   = (const float*)d_in[20];
    const float* s_Ri   = (const float*)d_in[21];
    const float* s_Rf   = (const float*)d_in[22];
    const float* s_Ro   = (const float*)d_in[23];
    const float* s_Wp   = (const float*)d_in[24];
    const float* fcW    = (const float*)d_in[25];
    const float* fcb    = (const float*)d_in[26];

    float* ws = (float*)d_ws;
    float* x     = ws;                         // fp32 [8192][256]
    float* gi    = x + SZ;                     // fp32 [8192][4]
    float* gf    = gi + (size_t)BT * 4;
    float* a_arr = gf + (size_t)BT * 4;        // fp32 [128][256]
    float* M_arr = a_arr + 32768;
    unsigned short* xn  = (unsigned short*)(M_arr + 32768);  // bf16 [8192][256]
    unsigned short* hb  = xn + SZ;
    unsigned short* g0u = hb + SZ;             // q/z
    unsigned short* g1u = g0u + SZ;            // k/i
    unsigned short* g2u = g1u + SZ;            // v/f
    unsigned short* g3u = g2u + SZ;            // o/o
    unsigned short* Wt  = g3u + SZ;            // bf16 15x[256][256]

    conv_w<<<dim3(4, 4, 15), 256, 0, stream>>>(m_Wq, m_Wk, m_Wv, m_Wo, m_Wp,
                                               s_Wz, s_Wi, s_Wf, s_Wo, s_Wp, Wt);
    build_x<<<8192, 256, 0, stream>>>(X, dyad, embed, x);

    dim3 gg(128, 4);

    auto mlstm = [&](int L) {
        layernorm<<<BT, 256, 0, stream>>>(x, m_ln_g + L * 256, m_ln_b + L * 256, xn);
        gemm_mfma_bf16<<<dim3(128, 4, 4), 256, 0, stream>>>(
            xn, Wt, L * 10, g0u, 1.f, 0.125f, 1.f, 1.f);
        gate_gemm<<<BT / 64, 256, 0, stream>>>(xn, m_Wi + L * 1024, m_Wf + L * 1024,
                                               m_bi + L * 4, m_bf + L * 4, gi, gf);
        scan_am<<<128, 256, 0, stream>>>(gi, gf, a_arr, M_arr);
        mlstm_attn<<<gg, 256, 0, stream>>>(g0u, g1u, g2u, g3u, a_arr, M_arr, hb);
        gemm_mfma_f32<<<dim3(128, 4, 1), 256, 0, stream>>>(hb, Wt, L * 10 + 4, x, x);
    };

    mlstm(0);

    layernorm<<<BT, 256, 0, stream>>>(x, s_ln_g, s_ln_b, xn);
    gemm_mfma_bf16<<<dim3(128, 4, 4), 256, 0, stream>>>(
        xn, Wt, 5, g0u, 1.f, 1.f, 1.f, 1.f);
    slstm_scan<<<4, 512, 0, stream>>>(g0u, g1u, g2u, g3u,
                                      s_Rz, s_Ri, s_Rf, s_Ro, hb);
    gemm_mfma_f32<<<dim3(128, 4, 1), 256, 0, stream>>>(hb, Wt, 9, x, x);

    mlstm(1);

    fc_kernel<<<32, 64, 0, stream>>>(x, fcW, fcb, (float*)d_out);
}

// Round 7
// 390.354 us; speedup vs baseline: 1.3555x; 1.3555x over previous
//
#include <hip/hip_runtime.h>
#include <hip/hip_bf16.h>
#include <hip/hip_fp16.h>

// ---------------------------------------------------------------------------
// DyadXLSTM forward. fp32 in/out; bf16 activations into MFMA GEMMs.
// mLSTM recurrence computed as chunked causal attention (exact rewrite):
//   F_t = cumsum(fp), a_t = ip_t - F_t, M_t = max(0, prefix-max a),
//   P_tj = exp(a_j - M_t) * (q_t . k_j)  [j<=t],  h = sig(o) * P V / max(|rowsum P|,1)
// sLSTM: r0's 4-wave structure (1 gate/wave, f32 LDS exchange, 1 barrier/step)
// with the R column held in 32 NAMED u32 scalars (half2-packed d-pairs).
// Arrays were scratch-backed in every prior variant (r0: VGPR=44 w/ r[64]!);
// named scalars are the one form the allocator must keep in registers.
// Matvec: DPP lane^1 pack + 32 readlane + 32 v_pk_fma_f16.
// B=32 T=256 NH=4 DH=64 D=H=256, BT=8192.
// ---------------------------------------------------------------------------

#define BT 8192
#define SZ ((size_t)BT * 256)

typedef __attribute__((ext_vector_type(4))) float  f32x4;
typedef __attribute__((ext_vector_type(8))) short  s16x8;

__device__ __forceinline__ float bf2f(unsigned short u) {
    return __uint_as_float(((unsigned int)u) << 16);
}
__device__ __forceinline__ unsigned short f2bf(float f) {
    __hip_bfloat16 h = __float2bfloat16(f);
    return *(unsigned short*)&h;
}
__device__ __forceinline__ unsigned int packh2(float a, float b) {
    __half2 h = __floats2half2_rn(a, b);
    union { __half2 h2; unsigned int u; } c; c.h2 = h;
    return c.u;
}
__device__ __forceinline__ __half2 u2h(unsigned int u) {
    union { unsigned int u; __half2 h2; } c; c.u = u;
    return c.h2;
}

// ---------------------------------------------------------------------------
// Convert+transpose 15 weight matrices (256x256 fp32 K-major) -> bf16 Wt[slot][N][K]
__global__ __launch_bounds__(256) void conv_w(
    const float* mWq, const float* mWk, const float* mWv, const float* mWo,
    const float* mWp, const float* sWz, const float* sWi, const float* sWf,
    const float* sWo, const float* sWp, unsigned short* __restrict__ Wt)
{
    int z = blockIdx.z;
    const float* mp[5] = {mWq, mWk, mWv, mWo, mWp};
    const float* sp[5] = {sWz, sWi, sWf, sWo, sWp};
    const float* src;
    if (z < 5)       src = mp[z];
    else if (z < 10) src = sp[z - 5];
    else             src = mp[z - 10] + 65536;
    int kB = blockIdx.x * 64, nB = blockIdx.y * 64;
    __shared__ unsigned short Ts[64][68];
    int tid = threadIdx.x;
    int r = tid >> 2, c = (tid & 3) * 16;
    #pragma unroll
    for (int j = 0; j < 16; j += 4) {
        float4 wv = *(const float4*)(src + (size_t)(kB + r) * 256 + nB + c + j);
        Ts[r][c + j]     = f2bf(wv.x); Ts[r][c + j + 1] = f2bf(wv.y);
        Ts[r][c + j + 2] = f2bf(wv.z); Ts[r][c + j + 3] = f2bf(wv.w);
    }
    __syncthreads();
    int n = tid >> 2, k0 = (tid & 3) * 16;
    __attribute__((aligned(16))) unsigned short tmp[16];
    #pragma unroll
    for (int j = 0; j < 16; ++j) tmp[j] = Ts[k0 + j][n];
    unsigned short* dst = Wt + (size_t)z * 65536 + (size_t)(nB + n) * 256 + kB + k0;
    *(uint4*)dst       = *(const uint4*)tmp;
    *(uint4*)(dst + 8) = *(const uint4*)(tmp + 8);
}

// ---------------------------------------------------------------------------
__global__ __launch_bounds__(256) void build_x(
    const float* __restrict__ X, const int* __restrict__ dyad,
    const float* __restrict__ embed, float* __restrict__ x)
{
    int i = blockIdx.x * 256 + threadIdx.x;
    int d = i & 255, bt = i >> 8, b = bt >> 8;
    x[i] = (d < 224) ? X[bt * 224 + d] : embed[dyad[b] * 32 + (d - 224)];
}

// ---------------------------------------------------------------------------
__global__ __launch_bounds__(256) void layernorm(
    const float* __restrict__ x, const float* __restrict__ g,
    const float* __restrict__ b, unsigned short* __restrict__ xn)
{
    int row = blockIdx.x, tid = threadIdx.x;
    float v = x[(size_t)row * 256 + tid];
    float s = v, s2 = v * v;
    #pragma unroll
    for (int o = 32; o; o >>= 1) { s += __shfl_xor(s, o); s2 += __shfl_xor(s2, o); }
    __shared__ float ls[8];
    int wave = tid >> 6, lane = tid & 63;
    if (lane == 0) { ls[wave] = s; ls[4 + wave] = s2; }
    __syncthreads();
    s  = ls[0] + ls[1] + ls[2] + ls[3];
    s2 = ls[4] + ls[5] + ls[6] + ls[7];
    float mu  = s * (1.f / 256.f);
    float var = s2 * (1.f / 256.f) - mu * mu;
    float inv = rsqrtf(var + 1e-5f);
    xn[(size_t)row * 256 + tid] = f2bf((v - mu) * inv * g[tid] + b[tid]);
}

// ---------------------------------------------------------------------------
// bf16-out GEMM: out[z][8192][256](bf16) = alpha_z * A(bf16) @ Wt[slot0+z]^T
__global__ __launch_bounds__(256) void gemm_mfma_bf16(
    const unsigned short* __restrict__ A, const unsigned short* __restrict__ Wt,
    int slot0, unsigned short* out0, float a0, float a1, float a2, float a3)
{
    __shared__ unsigned short As[64 * 40];
    __shared__ unsigned short Bs[64 * 40];
    int tid = threadIdx.x, bz = blockIdx.z;
    const unsigned short* W = Wt + (size_t)(slot0 + bz) * 65536;
    unsigned short* out = out0 + (size_t)bz * SZ;
    float alpha = bz == 0 ? a0 : bz == 1 ? a1 : bz == 2 ? a2 : a3;
    int rowBase = blockIdx.x * 64, colBase = blockIdx.y * 64;
    int srow = tid >> 2, scol = (tid & 3) * 8;
    const unsigned short* Ap = A + (size_t)(rowBase + srow) * 256 + scol;
    const unsigned short* Wp = W + (size_t)(colBase + srow) * 256 + scol;
    unsigned short* Asw = As + srow * 40 + scol;
    unsigned short* Bsw = Bs + srow * 40 + scol;
    int w = tid >> 6, lane = tid & 63, quad = lane >> 4, l15 = lane & 15;
    const unsigned short* Ar  = As + (w * 16 + l15) * 40 + quad * 8;
    const unsigned short* Br0 = Bs + l15 * 40 + quad * 8;
    f32x4 acc[4];
    #pragma unroll
    for (int c = 0; c < 4; ++c) acc[c] = (f32x4){0.f, 0.f, 0.f, 0.f};
    for (int k0 = 0; k0 < 256; k0 += 32) {
        uint4 av = *(const uint4*)(Ap + k0);
        uint4 bv = *(const uint4*)(Wp + k0);
        __syncthreads();
        *(uint4*)Asw = av;
        *(uint4*)Bsw = bv;
        __syncthreads();
        s16x8 af = *(const s16x8*)Ar;
        #pragma unroll
        for (int c = 0; c < 4; ++c) {
            s16x8 bf = *(const s16x8*)(Br0 + c * 16 * 40);
            acc[c] = __builtin_amdgcn_mfma_f32_16x16x32_bf16(af, bf, acc[c], 0, 0, 0);
        }
    }
    #pragma unroll
    for (int c = 0; c < 4; ++c) {
        int col  = colBase + c * 16 + l15;
        int row0 = rowBase + w * 16 + quad * 4;
        #pragma unroll
        for (int i2 = 0; i2 < 4; ++i2)
            out[(size_t)(row0 + i2) * 256 + col] = f2bf(alpha * acc[c][i2]);
    }
}

// ---------------------------------------------------------------------------
// fp32-out GEMM with residual: out = A(bf16) @ Wt[slot]^T + Res
__global__ __launch_bounds__(256) void gemm_mfma_f32(
    const unsigned short* __restrict__ A, const unsigned short* __restrict__ Wt,
    int slot, float* __restrict__ out, const float* __restrict__ Res)
{
    __shared__ unsigned short As[64 * 40];
    __shared__ unsigned short Bs[64 * 40];
    int tid = threadIdx.x;
    const unsigned short* W = Wt + (size_t)slot * 65536;
    int rowBase = blockIdx.x * 64, colBase = blockIdx.y * 64;
    int srow = tid >> 2, scol = (tid & 3) * 8;
    const unsigned short* Ap = A + (size_t)(rowBase + srow) * 256 + scol;
    const unsigned short* Wp = W + (size_t)(colBase + srow) * 256 + scol;
    unsigned short* Asw = As + srow * 40 + scol;
    unsigned short* Bsw = Bs + srow * 40 + scol;
    int w = tid >> 6, lane = tid & 63, quad = lane >> 4, l15 = lane & 15;
    const unsigned short* Ar  = As + (w * 16 + l15) * 40 + quad * 8;
    const unsigned short* Br0 = Bs + l15 * 40 + quad * 8;
    f32x4 acc[4];
    #pragma unroll
    for (int c = 0; c < 4; ++c) acc[c] = (f32x4){0.f, 0.f, 0.f, 0.f};
    for (int k0 = 0; k0 < 256; k0 += 32) {
        uint4 av = *(const uint4*)(Ap + k0);
        uint4 bv = *(const uint4*)(Wp + k0);
        __syncthreads();
        *(uint4*)Asw = av;
        *(uint4*)Bsw = bv;
        __syncthreads();
        s16x8 af = *(const s16x8*)Ar;
        #pragma unroll
        for (int c = 0; c < 4; ++c) {
            s16x8 bf = *(const s16x8*)(Br0 + c * 16 * 40);
            acc[c] = __builtin_amdgcn_mfma_f32_16x16x32_bf16(af, bf, acc[c], 0, 0, 0);
        }
    }
    #pragma unroll
    for (int c = 0; c < 4; ++c) {
        int col  = colBase + c * 16 + l15;
        int row0 = rowBase + w * 16 + quad * 4;
        #pragma unroll
        for (int i2 = 0; i2 < 4; ++i2) {
            size_t idx = (size_t)(row0 + i2) * 256 + col;
            out[idx] = acc[c][i2] + Res[idx];
        }
    }
}

// ---------------------------------------------------------------------------
// gi/gf[row,h] = xn[row,:].W{i,f}[:,h] + b{i,f}[h]
__global__ __launch_bounds__(256) void gate_gemm(
    const unsigned short* __restrict__ xn,
    const float* __restrict__ Wi, const float* __restrict__ Wf,
    const float* __restrict__ bi, const float* __restrict__ bf_,
    float* __restrict__ gi, float* __restrict__ gf)
{
    int tid = threadIdx.x;
    int hh = tid & 3;
    int row = blockIdx.x * 64 + (tid >> 2);
    float ai = bi[hh], af = bf_[hh];
    const unsigned short* xr = xn + (size_t)row * 256;
    for (int k2 = 0; k2 < 256; ++k2) {
        float xv = bf2f(xr[k2]);
        ai += xv * Wi[k2 * 4 + hh];
        af += xv * Wf[k2 * 4 + hh];
    }
    gi[row * 4 + hh] = ai;
    gf[row * 4 + hh] = af;
}

// ---------------------------------------------------------------------------
// Per-(b,h): F = cumsum(fp); a = ip - F; M = max(0, prefix-max(a)).
// One block per bh, thread = t, Hillis-Steele scans in LDS.
__global__ __launch_bounds__(256) void scan_am(
    const float* __restrict__ gi, const float* __restrict__ gf,
    float* __restrict__ a_arr, float* __restrict__ M_arr)
{
    int bh = blockIdx.x, b = bh >> 2, h = bh & 3;
    int t = threadIdx.x;
    float fp = gf[(b * 256 + t) * 4 + h];
    float ip = gi[(b * 256 + t) * 4 + h];
    __shared__ float buf[256];
    buf[t] = fp;
    __syncthreads();
    #pragma unroll
    for (int o = 1; o < 256; o <<= 1) {
        float add = (t >= o) ? buf[t - o] : 0.f;
        __syncthreads();
        buf[t] += add;
        __syncthreads();
    }
    float F = buf[t];
    float a = ip - F;
    __syncthreads();
    buf[t] = a;
    __syncthreads();
    #pragma unroll
    for (int o = 1; o < 256; o <<= 1) {
        float mx = (t >= o) ? buf[t - o] : -3.4e38f;
        __syncthreads();
        buf[t] = fmaxf(buf[t], mx);
        __syncthreads();
    }
    a_arr[bh * 256 + t] = a;
    M_arr[bh * 256 + t] = fmaxf(buf[t], 0.f);
}

// ---------------------------------------------------------------------------
// mLSTM as causal decay-attention. Block = (bh, row-tile rt of 64).
// 4 waves; wave w owns rows [16w,16w+16) of the row tile.
__global__ __launch_bounds__(256) void mlstm_attn(
    const unsigned short* __restrict__ qb, const unsigned short* __restrict__ kb,
    const unsigned short* __restrict__ vb, const unsigned short* __restrict__ ob,
    const float* __restrict__ a_arr, const float* __restrict__ M_arr,
    unsigned short* __restrict__ hout)
{
    int bh = blockIdx.x, rt = blockIdx.y;
    int b = bh >> 2, h = bh & 3;
    int tid = threadIdx.x, w = tid >> 6, lane = tid & 63;
    int quad = lane >> 4, l15 = lane & 15;
    __shared__ unsigned short Qs[64][72];
    __shared__ unsigned short Ks[64][72];
    __shared__ unsigned short Vt[64][72];      // V transposed: [d][j]
    __shared__ unsigned short Ps[4][16][72];   // per-wave P strip
    __shared__ float a_s[64], M_s[64];
    int sr = tid >> 2, sc = (tid & 3) * 16;
    size_t qoff = (size_t)(b * 256 + rt * 64 + sr) * 256 + h * 64 + sc;
    *(uint4*)&Qs[sr][sc]     = *(const uint4*)(qb + qoff);
    *(uint4*)&Qs[sr][sc + 8] = *(const uint4*)(qb + qoff + 8);
    if (tid < 64) M_s[tid] = M_arr[bh * 256 + rt * 64 + tid];
    f32x4 accN[4];
    #pragma unroll
    for (int c = 0; c < 4; ++c) accN[c] = (f32x4){0.f, 0.f, 0.f, 0.f};
    f32x4 den = (f32x4){0.f, 0.f, 0.f, 0.f};
    int rowT = w * 16 + quad * 4;              // row within 64-tile (+i2)
    for (int ct = 0; ct <= rt; ++ct) {
        // stage K, V^T, a for this j-tile
        size_t koff = (size_t)(b * 256 + ct * 64 + sr) * 256 + h * 64 + sc;
        uint4 kv0 = *(const uint4*)(kb + koff);
        uint4 kv1 = *(const uint4*)(kb + koff + 8);
        uint4 vv0 = *(const uint4*)(vb + koff);
        uint4 vv1 = *(const uint4*)(vb + koff + 8);
        *(uint4*)&Ks[sr][sc]     = kv0;
        *(uint4*)&Ks[sr][sc + 8] = kv1;
        __attribute__((aligned(16))) unsigned short vt[16];
        *(uint4*)vt = vv0; *(uint4*)(vt + 8) = vv1;
        #pragma unroll
        for (int jj = 0; jj < 16; ++jj) Vt[sc + jj][sr] = vt[jj];
        if (tid < 64) a_s[tid] = a_arr[bh * 256 + ct * 64 + tid];
        __syncthreads();
        // S = Q K^T (16x64 strip per wave)
        f32x4 S[4];
        #pragma unroll
        for (int c = 0; c < 4; ++c) S[c] = (f32x4){0.f, 0.f, 0.f, 0.f};
        #pragma unroll
        for (int ks = 0; ks < 2; ++ks) {
            s16x8 af = *(const s16x8*)&Qs[w * 16 + l15][quad * 8 + ks * 32];
            #pragma unroll
            for (int c = 0; c < 4; ++c) {
                s16x8 bfr = *(const s16x8*)&Ks[c * 16 + l15][quad * 8 + ks * 32];
                S[c] = __builtin_amdgcn_mfma_f32_16x16x32_bf16(af, bfr, S[c], 0, 0, 0);
            }
        }
        // scale by exp(a_j - M_t), causal mask on diagonal tile, rowsum
        bool dg = (ct == rt);
        #pragma unroll
        for (int c = 0; c < 4; ++c) {
            int col = c * 16 + l15;
            #pragma unroll
            for (int i2 = 0; i2 < 4; ++i2) {
                int row = rowT + i2;
                float p = S[c][i2] * __expf(a_s[col] - M_s[row]);
                if (dg && col > row) p = 0.f;
                S[c][i2] = p;
                den[i2] += p;
            }
        }
        // P -> LDS (bf16) for A-fragment relayout
        #pragma unroll
        for (int c = 0; c < 4; ++c)
            #pragma unroll
            for (int i2 = 0; i2 < 4; ++i2)
                Ps[w][quad * 4 + i2][c * 16 + l15] = f2bf(S[c][i2]);
        __syncthreads();
        // num += P V
        #pragma unroll
        for (int ks = 0; ks < 2; ++ks) {
            s16x8 af = *(const s16x8*)&Ps[w][l15][quad * 8 + ks * 32];
            #pragma unroll
            for (int c = 0; c < 4; ++c) {
                s16x8 bfr = *(const s16x8*)&Vt[c * 16 + l15][quad * 8 + ks * 32];
                accN[c] = __builtin_amdgcn_mfma_f32_16x16x32_bf16(af, bfr, accN[c], 0, 0, 0);
            }
        }
        __syncthreads();
    }
    // reduce den across the 16 lanes sharing rows (l15 dimension)
    #pragma unroll
    for (int ofs = 1; ofs < 16; ofs <<= 1) {
        den[0] += __shfl_xor(den[0], ofs);
        den[1] += __shfl_xor(den[1], ofs);
        den[2] += __shfl_xor(den[2], ofs);
        den[3] += __shfl_xor(den[3], ofs);
    }
    // epilogue: h = sigmoid(o) * num / max(|den|,1)
    #pragma unroll
    for (int c = 0; c < 4; ++c) {
        int d = c * 16 + l15;
        #pragma unroll
        for (int i2 = 0; i2 < 4; ++i2) {
            size_t idx = (size_t)(b * 256 + rt * 64 + rowT + i2) * 256 + h * 64 + d;
            float ov = bf2f(ob[idx]);
            float sg = 1.f / (1.f + __expf(-ov));
            float dn = fmaxf(fabsf(den[i2]), 1.f);
            hout[idx] = f2bf(sg * accN[c][i2] / dn);
        }
    }
}

// ---------------------------------------------------------------------------
// sLSTM scan. r0 structure: block=(b,h), 4 waves, wave w owns gate w; lane=e.
// R column e held in 32 NAMED u32 scalars (half2 d-pairs) -- no array, so the
// allocator cannot scratch-back it (r0 had float r[64] at VGPR=44 => scratch
// reloads every step, ~1.7x VALU inflation). Matvec: DPP lane^1 pack +
// 32 readlane + 32 v_pk_fma_f16. Preact exchange via f32 LDS, 1 barrier/step.
#define REP32(M) M(0) M(1) M(2) M(3) M(4) M(5) M(6) M(7) M(8) M(9) M(10) M(11) \
  M(12) M(13) M(14) M(15) M(16) M(17) M(18) M(19) M(20) M(21) M(22) M(23) \
  M(24) M(25) M(26) M(27) M(28) M(29) M(30) M(31)

__global__ __launch_bounds__(256) void slstm_scan(
    const unsigned short* __restrict__ zx, const unsigned short* __restrict__ ix,
    const unsigned short* __restrict__ fx, const unsigned short* __restrict__ ox,
    const float* __restrict__ Rz, const float* __restrict__ Ri,
    const float* __restrict__ Rf, const float* __restrict__ Ro,
    unsigned short* __restrict__ hout)
{
    int bh = blockIdx.x, b = bh >> 2, h = bh & 3;
    int tid = threadIdx.x, w = tid >> 6, e = tid & 63;
    const float* Rc = (w == 0 ? Rz : w == 1 ? Ri : w == 2 ? Rf : Ro) + h * 4096 + e;
    // 32 named half2 regs: rp_j = (R[2j][e], R[2j+1][e])
#define DECL_RP(j) unsigned int rp##j;
    REP32(DECL_RP)
#define INIT_RP(j) rp##j = packh2(Rc[(2*(j))*64], Rc[(2*(j)+1)*64]);
    REP32(INIT_RP)
    const unsigned short* xin = (w == 0 ? zx : w == 1 ? ix : w == 2 ? fx : ox);
    __shared__ float gl[2][4][64];
    float c = 0.f, n = 0.f, m = 0.f, hv = 0.f;
    size_t base = (size_t)b * 65536 + h * 64 + e;
    float gx = bf2f(xin[base]);
    for (int t = 0; t < 256; ++t) {
        // pair-pack h via DPP lane^1: even lane 2j holds (h[2j], h[2j+1])
        float hn = __int_as_float(__builtin_amdgcn_mov_dpp(
            __float_as_int(hv), 0xB1, 0xF, 0xF, true));
        unsigned int hbits = packh2(hv, hn);
        __half2 accA = __float2half2_rn(0.f), accB = __float2half2_rn(0.f);
#define FMA_RP(j) { unsigned int cj = (unsigned int)__builtin_amdgcn_readlane((int)hbits, 2*(j)); \
        if ((j) & 1) accB = __hfma2(u2h(cj), u2h(rp##j), accB); \
        else         accA = __hfma2(u2h(cj), u2h(rp##j), accA); }
        REP32(FMA_RP)
        __half2 acc = __hadd2(accA, accB);
        gl[t & 1][w][e] = gx + __low2float(acc) + __high2float(acc);
        int tn = (t + 1 < 256) ? t + 1 : t;
        float gxn = bf2f(xin[base + (size_t)tn * 256]);
        __syncthreads();
        float zp = gl[t & 1][0][e], ip = gl[t & 1][1][e];
        float fp = gl[t & 1][2][e], op = gl[t & 1][3][e];
        float ez = __expf(2.f * zp);
        float z  = 1.f - 2.f / (ez + 1.f);          // tanh
        float mn = fmaxf(fp + m, ip);
        float i_s = __expf(ip - mn), f_s = __expf(fp + m - mn);
        m = mn;
        c = f_s * c + i_s * z;
        n = f_s * n + i_s;
        hv = c / (n * (1.f + __expf(-op)));          // sigmoid(op)*c/n
        if (w == 0) hout[base + (size_t)t * 256] = f2bf(hv);
        gx = gxn;
    }
}

// ---------------------------------------------------------------------------
__global__ __launch_bounds__(64) void fc_kernel(
    const float* __restrict__ x, const float* __restrict__ fcW,
    const float* __restrict__ fcb, float* __restrict__ out)
{
    int b = blockIdx.x, lane = threadIdx.x;
    const float* xr = x + ((size_t)b * 256 + 255) * 256;
    float s = 0.f;
    #pragma unroll
    for (int j = 0; j < 4; ++j) { int d = j * 64 + lane; s += xr[d] * fcW[d]; }
    #pragma unroll
    for (int ofs = 32; ofs; ofs >>= 1) s += __shfl_xor(s, ofs);
    if (lane == 0) out[b] = s + fcb[0];
}

// ---------------------------------------------------------------------------
extern "C" void kernel_launch(void* const* d_in, const int* in_sizes, int n_in,
                              void* d_out, int out_size, void* d_ws, size_t ws_size,
                              hipStream_t stream)
{
    const float* X      = (const float*)d_in[0];
    const int*   dyad   = (const int*)d_in[1];
    const float* embed  = (const float*)d_in[2];
    const float* m_ln_g = (const float*)d_in[3];
    const float* m_ln_b = (const float*)d_in[4];
    const float* m_Wq   = (const float*)d_in[5];
    const float* m_Wk   = (const float*)d_in[6];
    const float* m_Wv   = (const float*)d_in[7];
    const float* m_Wi   = (const float*)d_in[8];
    const float* m_Wf   = (const float*)d_in[9];
    const float* m_bi   = (const float*)d_in[10];
    const float* m_bf   = (const float*)d_in[11];
    const float* m_Wo   = (const float*)d_in[12];
    const float* m_Wp   = (const float*)d_in[13];
    const float* s_ln_g = (const float*)d_in[14];
    const float* s_ln_b = (const float*)d_in[15];
    const float* s_Wz   = (const float*)d_in[16];
    const float* s_Wi   = (const float*)d_in[17];
    const float* s_Wf   = (const float*)d_in[18];
    const float* s_Wo   = (const float*)d_in[19];
    const float* s_Rz   = (const float*)d_in[20];
    const float* s_Ri   = (const float*)d_in[21];
    const float* s_Rf   = (const float*)d_in[22];
    const float* s_Ro   = (const float*)d_in[23];
    const float* s_Wp   = (const float*)d_in[24];
    const float* fcW    = (const float*)d_in[25];
    const float* fcb    = (const float*)d_in[26];

    float* ws = (float*)d_ws;
    float* x     = ws;                         // fp32 [8192][256]
    float* gi    = x + SZ;                     // fp32 [8192][4]
    float* gf    = gi + (size_t)BT * 4;
    float* a_arr = gf + (size_t)BT * 4;        // fp32 [128][256]
    float* M_arr = a_arr + 32768;
    unsigned short* xn  = (unsigned short*)(M_arr + 32768);  // bf16 [8192][256]
    unsigned short* hb  = xn + SZ;
    unsigned short* g0u = hb + SZ;             // q/z
    unsigned short* g1u = g0u + SZ;            // k/i
    unsigned short* g2u = g1u + SZ;            // v/f
    unsigned short* g3u = g2u + SZ;            // o/o
    unsigned short* Wt  = g3u + SZ;            // bf16 15x[256][256]

    conv_w<<<dim3(4, 4, 15), 256, 0, stream>>>(m_Wq, m_Wk, m_Wv, m_Wo, m_Wp,
                                               s_Wz, s_Wi, s_Wf, s_Wo, s_Wp, Wt);
    build_x<<<8192, 256, 0, stream>>>(X, dyad, embed, x);

    dim3 gg(128, 4);

    auto mlstm = [&](int L) {
        layernorm<<<BT, 256, 0, stream>>>(x, m_ln_g + L * 256, m_ln_b + L * 256, xn);
        gemm_mfma_bf16<<<dim3(128, 4, 4), 256, 0, stream>>>(
            xn, Wt, L * 10, g0u, 1.f, 0.125f, 1.f, 1.f);
        gate_gemm<<<BT / 64, 256, 0, stream>>>(xn, m_Wi + L * 1024, m_Wf + L * 1024,
                                               m_bi + L * 4, m_bf + L * 4, gi, gf);
        scan_am<<<128, 256, 0, stream>>>(gi, gf, a_arr, M_arr);
        mlstm_attn<<<gg, 256, 0, stream>>>(g0u, g1u, g2u, g3u, a_arr, M_arr, hb);
        gemm_mfma_f32<<<dim3(128, 4, 1), 256, 0, stream>>>(hb, Wt, L * 10 + 4, x, x);
    };

    mlstm(0);

    layernorm<<<BT, 256, 0, stream>>>(x, s_ln_g, s_ln_b, xn);
    gemm_mfma_bf16<<<dim3(128, 4, 4), 256, 0, stream>>>(
        xn, Wt, 5, g0u, 1.f, 1.f, 1.f, 1.f);
    slstm_scan<<<128, 256, 0, stream>>>(g0u, g1u, g2u, g3u,
                                        s_Rz, s_Ri, s_Rf, s_Ro, hb);
    gemm_mfma_f32<<<dim3(128, 4, 1), 256, 0, stream>>>(hb, Wt, 9, x, x);

    mlstm(1);

    fc_kernel<<<32, 64, 0, stream>>>(x, fcW, fcb, (float*)d_out);
}

// Round 8
// 376.805 us; speedup vs baseline: 1.4042x; 1.0360x over previous
//
#include <hip/hip_runtime.h>
#include <hip/hip_bf16.h>
#include <hip/hip_fp16.h>

// ---------------------------------------------------------------------------
// DyadXLSTM forward. fp32 in/out; bf16 activations into MFMA GEMMs.
// mLSTM recurrence computed as chunked causal attention (exact rewrite):
//   F_t = cumsum(fp), a_t = ip_t - F_t, M_t = max(0, prefix-max a),
//   P_tj = exp(a_j - M_t) * (q_t . k_j)  [j<=t],  h = sig(o) * P V / max(|rowsum P|,1)
// sLSTM: 1 wave per (b,h), ALL 4 gate matvecs in-wave (no LDS, no barrier),
// with all 128 R d-pair registers as NAMED u32 scalars (r7 proved named
// scalars stay in VGPRs; r2's identical structure died of array->scratch).
// One DPP pack + 32 readlane shared across gates; 128 v_pk_fma_f16 in 8
// independent 16-deep chains; 4-deep global prefetch ring.
// B=32 T=256 NH=4 DH=64 D=H=256, BT=8192.
// ---------------------------------------------------------------------------

#define BT 8192
#define SZ ((size_t)BT * 256)

typedef __attribute__((ext_vector_type(4))) float  f32x4;
typedef __attribute__((ext_vector_type(8))) short  s16x8;

__device__ __forceinline__ float bf2f(unsigned short u) {
    return __uint_as_float(((unsigned int)u) << 16);
}
__device__ __forceinline__ unsigned short f2bf(float f) {
    __hip_bfloat16 h = __float2bfloat16(f);
    return *(unsigned short*)&h;
}
__device__ __forceinline__ unsigned int packh2(float a, float b) {
    __half2 h = __floats2half2_rn(a, b);
    union { __half2 h2; unsigned int u; } c; c.h2 = h;
    return c.u;
}
__device__ __forceinline__ __half2 u2h(unsigned int u) {
    union { unsigned int u; __half2 h2; } c; c.u = u;
    return c.h2;
}

// ---------------------------------------------------------------------------
// Convert+transpose 15 weight matrices (256x256 fp32 K-major) -> bf16 Wt[slot][N][K]
__global__ __launch_bounds__(256) void conv_w(
    const float* mWq, const float* mWk, const float* mWv, const float* mWo,
    const float* mWp, const float* sWz, const float* sWi, const float* sWf,
    const float* sWo, const float* sWp, unsigned short* __restrict__ Wt)
{
    int z = blockIdx.z;
    const float* mp[5] = {mWq, mWk, mWv, mWo, mWp};
    const float* sp[5] = {sWz, sWi, sWf, sWo, sWp};
    const float* src;
    if (z < 5)       src = mp[z];
    else if (z < 10) src = sp[z - 5];
    else             src = mp[z - 10] + 65536;
    int kB = blockIdx.x * 64, nB = blockIdx.y * 64;
    __shared__ unsigned short Ts[64][68];
    int tid = threadIdx.x;
    int r = tid >> 2, c = (tid & 3) * 16;
    #pragma unroll
    for (int j = 0; j < 16; j += 4) {
        float4 wv = *(const float4*)(src + (size_t)(kB + r) * 256 + nB + c + j);
        Ts[r][c + j]     = f2bf(wv.x); Ts[r][c + j + 1] = f2bf(wv.y);
        Ts[r][c + j + 2] = f2bf(wv.z); Ts[r][c + j + 3] = f2bf(wv.w);
    }
    __syncthreads();
    int n = tid >> 2, k0 = (tid & 3) * 16;
    __attribute__((aligned(16))) unsigned short tmp[16];
    #pragma unroll
    for (int j = 0; j < 16; ++j) tmp[j] = Ts[k0 + j][n];
    unsigned short* dst = Wt + (size_t)z * 65536 + (size_t)(nB + n) * 256 + kB + k0;
    *(uint4*)dst       = *(const uint4*)tmp;
    *(uint4*)(dst + 8) = *(const uint4*)(tmp + 8);
}

// ---------------------------------------------------------------------------
__global__ __launch_bounds__(256) void build_x(
    const float* __restrict__ X, const int* __restrict__ dyad,
    const float* __restrict__ embed, float* __restrict__ x)
{
    int i = blockIdx.x * 256 + threadIdx.x;
    int d = i & 255, bt = i >> 8, b = bt >> 8;
    x[i] = (d < 224) ? X[bt * 224 + d] : embed[dyad[b] * 32 + (d - 224)];
}

// ---------------------------------------------------------------------------
__global__ __launch_bounds__(256) void layernorm(
    const float* __restrict__ x, const float* __restrict__ g,
    const float* __restrict__ b, unsigned short* __restrict__ xn)
{
    int row = blockIdx.x, tid = threadIdx.x;
    float v = x[(size_t)row * 256 + tid];
    float s = v, s2 = v * v;
    #pragma unroll
    for (int o = 32; o; o >>= 1) { s += __shfl_xor(s, o); s2 += __shfl_xor(s2, o); }
    __shared__ float ls[8];
    int wave = tid >> 6, lane = tid & 63;
    if (lane == 0) { ls[wave] = s; ls[4 + wave] = s2; }
    __syncthreads();
    s  = ls[0] + ls[1] + ls[2] + ls[3];
    s2 = ls[4] + ls[5] + ls[6] + ls[7];
    float mu  = s * (1.f / 256.f);
    float var = s2 * (1.f / 256.f) - mu * mu;
    float inv = rsqrtf(var + 1e-5f);
    xn[(size_t)row * 256 + tid] = f2bf((v - mu) * inv * g[tid] + b[tid]);
}

// ---------------------------------------------------------------------------
// bf16-out GEMM: out[z][8192][256](bf16) = alpha_z * A(bf16) @ Wt[slot0+z]^T
__global__ __launch_bounds__(256) void gemm_mfma_bf16(
    const unsigned short* __restrict__ A, const unsigned short* __restrict__ Wt,
    int slot0, unsigned short* out0, float a0, float a1, float a2, float a3)
{
    __shared__ unsigned short As[64 * 40];
    __shared__ unsigned short Bs[64 * 40];
    int tid = threadIdx.x, bz = blockIdx.z;
    const unsigned short* W = Wt + (size_t)(slot0 + bz) * 65536;
    unsigned short* out = out0 + (size_t)bz * SZ;
    float alpha = bz == 0 ? a0 : bz == 1 ? a1 : bz == 2 ? a2 : a3;
    int rowBase = blockIdx.x * 64, colBase = blockIdx.y * 64;
    int srow = tid >> 2, scol = (tid & 3) * 8;
    const unsigned short* Ap = A + (size_t)(rowBase + srow) * 256 + scol;
    const unsigned short* Wp = W + (size_t)(colBase + srow) * 256 + scol;
    unsigned short* Asw = As + srow * 40 + scol;
    unsigned short* Bsw = Bs + srow * 40 + scol;
    int w = tid >> 6, lane = tid & 63, quad = lane >> 4, l15 = lane & 15;
    const unsigned short* Ar  = As + (w * 16 + l15) * 40 + quad * 8;
    const unsigned short* Br0 = Bs + l15 * 40 + quad * 8;
    f32x4 acc[4];
    #pragma unroll
    for (int c = 0; c < 4; ++c) acc[c] = (f32x4){0.f, 0.f, 0.f, 0.f};
    for (int k0 = 0; k0 < 256; k0 += 32) {
        uint4 av = *(const uint4*)(Ap + k0);
        uint4 bv = *(const uint4*)(Wp + k0);
        __syncthreads();
        *(uint4*)Asw = av;
        *(uint4*)Bsw = bv;
        __syncthreads();
        s16x8 af = *(const s16x8*)Ar;
        #pragma unroll
        for (int c = 0; c < 4; ++c) {
            s16x8 bf = *(const s16x8*)(Br0 + c * 16 * 40);
            acc[c] = __builtin_amdgcn_mfma_f32_16x16x32_bf16(af, bf, acc[c], 0, 0, 0);
        }
    }
    #pragma unroll
    for (int c = 0; c < 4; ++c) {
        int col  = colBase + c * 16 + l15;
        int row0 = rowBase + w * 16 + quad * 4;
        #pragma unroll
        for (int i2 = 0; i2 < 4; ++i2)
            out[(size_t)(row0 + i2) * 256 + col] = f2bf(alpha * acc[c][i2]);
    }
}

// ---------------------------------------------------------------------------
// fp32-out GEMM with residual: out = A(bf16) @ Wt[slot]^T + Res
__global__ __launch_bounds__(256) void gemm_mfma_f32(
    const unsigned short* __restrict__ A, const unsigned short* __restrict__ Wt,
    int slot, float* __restrict__ out, const float* __restrict__ Res)
{
    __shared__ unsigned short As[64 * 40];
    __shared__ unsigned short Bs[64 * 40];
    int tid = threadIdx.x;
    const unsigned short* W = Wt + (size_t)slot * 65536;
    int rowBase = blockIdx.x * 64, colBase = blockIdx.y * 64;
    int srow = tid >> 2, scol = (tid & 3) * 8;
    const unsigned short* Ap = A + (size_t)(rowBase + srow) * 256 + scol;
    const unsigned short* Wp = W + (size_t)(colBase + srow) * 256 + scol;
    unsigned short* Asw = As + srow * 40 + scol;
    unsigned short* Bsw = Bs + srow * 40 + scol;
    int w = tid >> 6, lane = tid & 63, quad = lane >> 4, l15 = lane & 15;
    const unsigned short* Ar  = As + (w * 16 + l15) * 40 + quad * 8;
    const unsigned short* Br0 = Bs + l15 * 40 + quad * 8;
    f32x4 acc[4];
    #pragma unroll
    for (int c = 0; c < 4; ++c) acc[c] = (f32x4){0.f, 0.f, 0.f, 0.f};
    for (int k0 = 0; k0 < 256; k0 += 32) {
        uint4 av = *(const uint4*)(Ap + k0);
        uint4 bv = *(const uint4*)(Wp + k0);
        __syncthreads();
        *(uint4*)Asw = av;
        *(uint4*)Bsw = bv;
        __syncthreads();
        s16x8 af = *(const s16x8*)Ar;
        #pragma unroll
        for (int c = 0; c < 4; ++c) {
            s16x8 bf = *(const s16x8*)(Br0 + c * 16 * 40);
            acc[c] = __builtin_amdgcn_mfma_f32_16x16x32_bf16(af, bf, acc[c], 0, 0, 0);
        }
    }
    #pragma unroll
    for (int c = 0; c < 4; ++c) {
        int col  = colBase + c * 16 + l15;
        int row0 = rowBase + w * 16 + quad * 4;
        #pragma unroll
        for (int i2 = 0; i2 < 4; ++i2) {
            size_t idx = (size_t)(row0 + i2) * 256 + col;
            out[idx] = acc[c][i2] + Res[idx];
        }
    }
}

// ---------------------------------------------------------------------------
// gi/gf[row,h] = xn[row,:].W{i,f}[:,h] + b{i,f}[h]
__global__ __launch_bounds__(256) void gate_gemm(
    const unsigned short* __restrict__ xn,
    const float* __restrict__ Wi, const float* __restrict__ Wf,
    const float* __restrict__ bi, const float* __restrict__ bf_,
    float* __restrict__ gi, float* __restrict__ gf)
{
    int tid = threadIdx.x;
    int hh = tid & 3;
    int row = blockIdx.x * 64 + (tid >> 2);
    float ai = bi[hh], af = bf_[hh];
    const unsigned short* xr = xn + (size_t)row * 256;
    for (int k2 = 0; k2 < 256; ++k2) {
        float xv = bf2f(xr[k2]);
        ai += xv * Wi[k2 * 4 + hh];
        af += xv * Wf[k2 * 4 + hh];
    }
    gi[row * 4 + hh] = ai;
    gf[row * 4 + hh] = af;
}

// ---------------------------------------------------------------------------
// Per-(b,h): F = cumsum(fp); a = ip - F; M = max(0, prefix-max(a)).
// One block per bh, thread = t, Hillis-Steele scans in LDS.
__global__ __launch_bounds__(256) void scan_am(
    const float* __restrict__ gi, const float* __restrict__ gf,
    float* __restrict__ a_arr, float* __restrict__ M_arr)
{
    int bh = blockIdx.x, b = bh >> 2, h = bh & 3;
    int t = threadIdx.x;
    float fp = gf[(b * 256 + t) * 4 + h];
    float ip = gi[(b * 256 + t) * 4 + h];
    __shared__ float buf[256];
    buf[t] = fp;
    __syncthreads();
    #pragma unroll
    for (int o = 1; o < 256; o <<= 1) {
        float add = (t >= o) ? buf[t - o] : 0.f;
        __syncthreads();
        buf[t] += add;
        __syncthreads();
    }
    float F = buf[t];
    float a = ip - F;
    __syncthreads();
    buf[t] = a;
    __syncthreads();
    #pragma unroll
    for (int o = 1; o < 256; o <<= 1) {
        float mx = (t >= o) ? buf[t - o] : -3.4e38f;
        __syncthreads();
        buf[t] = fmaxf(buf[t], mx);
        __syncthreads();
    }
    a_arr[bh * 256 + t] = a;
    M_arr[bh * 256 + t] = fmaxf(buf[t], 0.f);
}

// ---------------------------------------------------------------------------
// mLSTM as causal decay-attention. Block = (bh, row-tile rt of 64).
// 4 waves; wave w owns rows [16w,16w+16) of the row tile.
__global__ __launch_bounds__(256) void mlstm_attn(
    const unsigned short* __restrict__ qb, const unsigned short* __restrict__ kb,
    const unsigned short* __restrict__ vb, const unsigned short* __restrict__ ob,
    const float* __restrict__ a_arr, const float* __restrict__ M_arr,
    unsigned short* __restrict__ hout)
{
    int bh = blockIdx.x, rt = blockIdx.y;
    int b = bh >> 2, h = bh & 3;
    int tid = threadIdx.x, w = tid >> 6, lane = tid & 63;
    int quad = lane >> 4, l15 = lane & 15;
    __shared__ unsigned short Qs[64][72];
    __shared__ unsigned short Ks[64][72];
    __shared__ unsigned short Vt[64][72];      // V transposed: [d][j]
    __shared__ unsigned short Ps[4][16][72];   // per-wave P strip
    __shared__ float a_s[64], M_s[64];
    int sr = tid >> 2, sc = (tid & 3) * 16;
    size_t qoff = (size_t)(b * 256 + rt * 64 + sr) * 256 + h * 64 + sc;
    *(uint4*)&Qs[sr][sc]     = *(const uint4*)(qb + qoff);
    *(uint4*)&Qs[sr][sc + 8] = *(const uint4*)(qb + qoff + 8);
    if (tid < 64) M_s[tid] = M_arr[bh * 256 + rt * 64 + tid];
    f32x4 accN[4];
    #pragma unroll
    for (int c = 0; c < 4; ++c) accN[c] = (f32x4){0.f, 0.f, 0.f, 0.f};
    f32x4 den = (f32x4){0.f, 0.f, 0.f, 0.f};
    int rowT = w * 16 + quad * 4;              // row within 64-tile (+i2)
    for (int ct = 0; ct <= rt; ++ct) {
        // stage K, V^T, a for this j-tile
        size_t koff = (size_t)(b * 256 + ct * 64 + sr) * 256 + h * 64 + sc;
        uint4 kv0 = *(const uint4*)(kb + koff);
        uint4 kv1 = *(const uint4*)(kb + koff + 8);
        uint4 vv0 = *(const uint4*)(vb + koff);
        uint4 vv1 = *(const uint4*)(vb + koff + 8);
        *(uint4*)&Ks[sr][sc]     = kv0;
        *(uint4*)&Ks[sr][sc + 8] = kv1;
        __attribute__((aligned(16))) unsigned short vt[16];
        *(uint4*)vt = vv0; *(uint4*)(vt + 8) = vv1;
        #pragma unroll
        for (int jj = 0; jj < 16; ++jj) Vt[sc + jj][sr] = vt[jj];
        if (tid < 64) a_s[tid] = a_arr[bh * 256 + ct * 64 + tid];
        __syncthreads();
        // S = Q K^T (16x64 strip per wave)
        f32x4 S[4];
        #pragma unroll
        for (int c = 0; c < 4; ++c) S[c] = (f32x4){0.f, 0.f, 0.f, 0.f};
        #pragma unroll
        for (int ks = 0; ks < 2; ++ks) {
            s16x8 af = *(const s16x8*)&Qs[w * 16 + l15][quad * 8 + ks * 32];
            #pragma unroll
            for (int c = 0; c < 4; ++c) {
                s16x8 bfr = *(const s16x8*)&Ks[c * 16 + l15][quad * 8 + ks * 32];
                S[c] = __builtin_amdgcn_mfma_f32_16x16x32_bf16(af, bfr, S[c], 0, 0, 0);
            }
        }
        // scale by exp(a_j - M_t), causal mask on diagonal tile, rowsum
        bool dg = (ct == rt);
        #pragma unroll
        for (int c = 0; c < 4; ++c) {
            int col = c * 16 + l15;
            #pragma unroll
            for (int i2 = 0; i2 < 4; ++i2) {
                int row = rowT + i2;
                float p = S[c][i2] * __expf(a_s[col] - M_s[row]);
                if (dg && col > row) p = 0.f;
                S[c][i2] = p;
                den[i2] += p;
            }
        }
        // P -> LDS (bf16) for A-fragment relayout
        #pragma unroll
        for (int c = 0; c < 4; ++c)
            #pragma unroll
            for (int i2 = 0; i2 < 4; ++i2)
                Ps[w][quad * 4 + i2][c * 16 + l15] = f2bf(S[c][i2]);
        __syncthreads();
        // num += P V
        #pragma unroll
        for (int ks = 0; ks < 2; ++ks) {
            s16x8 af = *(const s16x8*)&Ps[w][l15][quad * 8 + ks * 32];
            #pragma unroll
            for (int c = 0; c < 4; ++c) {
                s16x8 bfr = *(const s16x8*)&Vt[c * 16 + l15][quad * 8 + ks * 32];
                accN[c] = __builtin_amdgcn_mfma_f32_16x16x32_bf16(af, bfr, accN[c], 0, 0, 0);
            }
        }
        __syncthreads();
    }
    // reduce den across the 16 lanes sharing rows (l15 dimension)
    #pragma unroll
    for (int ofs = 1; ofs < 16; ofs <<= 1) {
        den[0] += __shfl_xor(den[0], ofs);
        den[1] += __shfl_xor(den[1], ofs);
        den[2] += __shfl_xor(den[2], ofs);
        den[3] += __shfl_xor(den[3], ofs);
    }
    // epilogue: h = sigmoid(o) * num / max(|den|,1)
    #pragma unroll
    for (int c = 0; c < 4; ++c) {
        int d = c * 16 + l15;
        #pragma unroll
        for (int i2 = 0; i2 < 4; ++i2) {
            size_t idx = (size_t)(b * 256 + rt * 64 + rowT + i2) * 256 + h * 64 + d;
            float ov = bf2f(ob[idx]);
            float sg = 1.f / (1.f + __expf(-ov));
            float dn = fmaxf(fabsf(den[i2]), 1.f);
            hout[idx] = f2bf(sg * accN[c][i2] / dn);
        }
    }
}

// ---------------------------------------------------------------------------
// sLSTM scan. 1 wave per (b,h), lane = e; ALL 4 gates in-wave. 128 R d-pair
// registers as NAMED u32 scalars (proven VGPR-resident form, r7). Per step:
// 1 DPP + pack + 32 readlane (shared) + 128 v_pk_fma_f16 (8 indep 16-deep
// chains) + pointwise. No LDS, no barriers. 4-deep global prefetch ring.
#define REP32(M) M(0) M(1) M(2) M(3) M(4) M(5) M(6) M(7) M(8) M(9) M(10) M(11) \
  M(12) M(13) M(14) M(15) M(16) M(17) M(18) M(19) M(20) M(21) M(22) M(23) \
  M(24) M(25) M(26) M(27) M(28) M(29) M(30) M(31)

__global__ __launch_bounds__(64, 1) void slstm_scan(
    const unsigned short* __restrict__ zx, const unsigned short* __restrict__ ix,
    const unsigned short* __restrict__ fx, const unsigned short* __restrict__ ox,
    const float* __restrict__ Rz, const float* __restrict__ Ri,
    const float* __restrict__ Rf, const float* __restrict__ Ro,
    unsigned short* __restrict__ hout)
{
    int bh = blockIdx.x, b = bh >> 2, h = bh & 3;
    int e = threadIdx.x;            // 0..63 output element
    const float* R0 = Rz + h * 4096;
    const float* R1 = Ri + h * 4096;
    const float* R2 = Rf + h * 4096;
    const float* R3 = Ro + h * 4096;
#define DECL4(j) unsigned int rz##j, ri##j, rf##j, ro##j;
    REP32(DECL4)
#define INIT4(j) { int o0 = (2*(j))*64 + e, o1 = o0 + 64; \
    rz##j = packh2(R0[o0], R0[o1]); ri##j = packh2(R1[o0], R1[o1]); \
    rf##j = packh2(R2[o0], R2[o1]); ro##j = packh2(R3[o0], R3[o1]); }
    REP32(INIT4)
    float c = 0.f, n = 0.f, m = 0.f, hv = 0.f;
    size_t base = (size_t)b * 65536 + h * 64 + e;
    // 4-deep prefetch ring of raw bf16 gate inputs (static indices -> regs)
    unsigned short zr[4], ir[4], fr[4], orr[4];
    #pragma unroll
    for (int k = 0; k < 4; ++k) {
        size_t o = base + (size_t)k * 256;
        zr[k] = zx[o]; ir[k] = ix[o]; fr[k] = fx[o]; orr[k] = ox[o];
    }
    for (int t0 = 0; t0 < 256; t0 += 4) {
        #pragma unroll
        for (int k = 0; k < 4; ++k) {
            int t = t0 + k;
            float zv = bf2f(zr[k]), iv = bf2f(ir[k]);
            float fv = bf2f(fr[k]), ov = bf2f(orr[k]);
            // refill slot k for t+4 (issued early; consumed 4 steps later)
            int tn = t + 4; if (tn > 255) tn = 255;
            size_t nb = base + (size_t)tn * 256;
            zr[k] = zx[nb]; ir[k] = ix[nb]; fr[k] = fx[nb]; orr[k] = ox[nb];
            // lane^1 exchange via DPP quad_perm(1,0,3,2) -- pure VALU
            float hn = __int_as_float(__builtin_amdgcn_mov_dpp(
                __float_as_int(hv), 0xB1, 0xF, 0xF, true));
            unsigned int hbits = packh2(hv, hn);
            __half2 Z2h = __float2half2_rn(0.f);
            __half2 azA = Z2h, azB = Z2h, aiA = Z2h, aiB = Z2h;
            __half2 afA = Z2h, afB = Z2h, aoA = Z2h, aoB = Z2h;
#define FMA4(j) { unsigned int cj = (unsigned int)__builtin_amdgcn_readlane((int)hbits, 2*(j)); \
            __half2 hj = u2h(cj); \
            if ((j) & 1) { azB = __hfma2(hj, u2h(rz##j), azB); aiB = __hfma2(hj, u2h(ri##j), aiB); \
                           afB = __hfma2(hj, u2h(rf##j), afB); aoB = __hfma2(hj, u2h(ro##j), aoB); } \
            else         { azA = __hfma2(hj, u2h(rz##j), azA); aiA = __hfma2(hj, u2h(ri##j), aiA); \
                           afA = __hfma2(hj, u2h(rf##j), afA); aoA = __hfma2(hj, u2h(ro##j), aoA); } }
            REP32(FMA4)
            __half2 Az = __hadd2(azA, azB), Ai = __hadd2(aiA, aiB);
            __half2 Af = __hadd2(afA, afB), Ao = __hadd2(aoA, aoB);
            float zp  = zv + __low2float(Az) + __high2float(Az);
            float ip2 = iv + __low2float(Ai) + __high2float(Ai);
            float fp  = fv + __low2float(Af) + __high2float(Af);
            float op  = ov + __low2float(Ao) + __high2float(Ao);
            // gate nonlinearity (all f32, exact as before)
            float ez = __expf(2.f * zp);
            float z  = 1.f - 2.f / (ez + 1.f);          // tanh
            float mn = fmaxf(fp + m, ip2);
            float i_s = __expf(ip2 - mn), f_s = __expf(fp + m - mn);
            m = mn;
            c = f_s * c + i_s * z;
            n = f_s * n + i_s;
            hv = c / (n * (1.f + __expf(-op)));          // sigmoid(op)*c/n
            hout[base + (size_t)t * 256] = f2bf(hv);
        }
    }
}

// ---------------------------------------------------------------------------
__global__ __launch_bounds__(64) void fc_kernel(
    const float* __restrict__ x, const float* __restrict__ fcW,
    const float* __restrict__ fcb, float* __restrict__ out)
{
    int b = blockIdx.x, lane = threadIdx.x;
    const float* xr = x + ((size_t)b * 256 + 255) * 256;
    float s = 0.f;
    #pragma unroll
    for (int j = 0; j < 4; ++j) { int d = j * 64 + lane; s += xr[d] * fcW[d]; }
    #pragma unroll
    for (int ofs = 32; ofs; ofs >>= 1) s += __shfl_xor(s, ofs);
    if (lane == 0) out[b] = s + fcb[0];
}

// ---------------------------------------------------------------------------
extern "C" void kernel_launch(void* const* d_in, const int* in_sizes, int n_in,
                              void* d_out, int out_size, void* d_ws, size_t ws_size,
                              hipStream_t stream)
{
    const float* X      = (const float*)d_in[0];
    const int*   dyad   = (const int*)d_in[1];
    const float* embed  = (const float*)d_in[2];
    const float* m_ln_g = (const float*)d_in[3];
    const float* m_ln_b = (const float*)d_in[4];
    const float* m_Wq   = (const float*)d_in[5];
    const float* m_Wk   = (const float*)d_in[6];
    const float* m_Wv   = (const float*)d_in[7];
    const float* m_Wi   = (const float*)d_in[8];
    const float* m_Wf   = (const float*)d_in[9];
    const float* m_bi   = (const float*)d_in[10];
    const float* m_bf   = (const float*)d_in[11];
    const float* m_Wo   = (const float*)d_in[12];
    const float* m_Wp   = (const float*)d_in[13];
    const float* s_ln_g = (const float*)d_in[14];
    const float* s_ln_b = (const float*)d_in[15];
    const float* s_Wz   = (const float*)d_in[16];
    const float* s_Wi   = (const float*)d_in[17];
    const float* s_Wf   = (const float*)d_in[18];
    const float* s_Wo   = (const float*)d_in[19];
    const float* s_Rz   = (const float*)d_in[20];
    const float* s_Ri   = (const float*)d_in[21];
    const float* s_Rf   = (const float*)d_in[22];
    const float* s_Ro   = (const float*)d_in[23];
    const float* s_Wp   = (const float*)d_in[24];
    const float* fcW    = (const float*)d_in[25];
    const float* fcb    = (const float*)d_in[26];

    float* ws = (float*)d_ws;
    float* x     = ws;                         // fp32 [8192][256]
    float* gi    = x + SZ;                     // fp32 [8192][4]
    float* gf    = gi + (size_t)BT * 4;
    float* a_arr = gf + (size_t)BT * 4;        // fp32 [128][256]
    float* M_arr = a_arr + 32768;
    unsigned short* xn  = (unsigned short*)(M_arr + 32768);  // bf16 [8192][256]
    unsigned short* hb  = xn + SZ;
    unsigned short* g0u = hb + SZ;             // q/z
    unsigned short* g1u = g0u + SZ;            // k/i
    unsigned short* g2u = g1u + SZ;            // v/f
    unsigned short* g3u = g2u + SZ;            // o/o
    unsigned short* Wt  = g3u + SZ;            // bf16 15x[256][256]

    conv_w<<<dim3(4, 4, 15), 256, 0, stream>>>(m_Wq, m_Wk, m_Wv, m_Wo, m_Wp,
                                               s_Wz, s_Wi, s_Wf, s_Wo, s_Wp, Wt);
    build_x<<<8192, 256, 0, stream>>>(X, dyad, embed, x);

    dim3 gg(128, 4);

    auto mlstm = [&](int L) {
        layernorm<<<BT, 256, 0, stream>>>(x, m_ln_g + L * 256, m_ln_b + L * 256, xn);
        gemm_mfma_bf16<<<dim3(128, 4, 4), 256, 0, stream>>>(
            xn, Wt, L * 10, g0u, 1.f, 0.125f, 1.f, 1.f);
        gate_gemm<<<BT / 64, 256, 0, stream>>>(xn, m_Wi + L * 1024, m_Wf + L * 1024,
                                               m_bi + L * 4, m_bf + L * 4, gi, gf);
        scan_am<<<128, 256, 0, stream>>>(gi, gf, a_arr, M_arr);
        mlstm_attn<<<gg, 256, 0, stream>>>(g0u, g1u, g2u, g3u, a_arr, M_arr, hb);
        gemm_mfma_f32<<<dim3(128, 4, 1), 256, 0, stream>>>(hb, Wt, L * 10 + 4, x, x);
    };

    mlstm(0);

    layernorm<<<BT, 256, 0, stream>>>(x, s_ln_g, s_ln_b, xn);
    gemm_mfma_bf16<<<dim3(128, 4, 4), 256, 0, stream>>>(
        xn, Wt, 5, g0u, 1.f, 1.f, 1.f, 1.f);
    slstm_scan<<<128, 64, 0, stream>>>(g0u, g1u, g2u, g3u,
                                       s_Rz, s_Ri, s_Rf, s_Ro, hb);
    gemm_mfma_f32<<<dim3(128, 4, 1), 256, 0, stream>>>(hb, Wt, 9, x, x);

    mlstm(1);

    fc_kernel<<<32, 64, 0, stream>>>(x, fcW, fcb, (float*)d_out);
}